// Round 2
// baseline (1911.908 us; speedup 1.0000x reference)
//
#include <hip/hip_runtime.h>
#include <math.h>

#define NN   100000
#define NE   1000000
#define CIN  128
#define COUT 64
#define BN_EPS 1e-5f

// ---- workspace layout (4-byte element offsets) ----
#define Y1_OFF     0                       // NN*COUT floats
#define COL_OFF    6400000                 // NE ints
#define ROWPTR_OFF 7400000                 // NN+1 ints
#define CURSOR_OFF 7500004                 // NN ints
#define DEG_OFF    7600004                 // NN ints
#define W1P_OFF    7700004                 // 3*CIN*COUT floats
#define C1_OFF     (W1P_OFF + 3*CIN*COUT)
#define INSUM_OFF  (C1_OFF + 3*COUT)
#define INSQ_OFF   (INSUM_OFF + CIN)
#define OSUM_OFF   (INSQ_OFF + CIN)
#define OSQ_OFF    (OSUM_OFF + 3*COUT)
#define SCALE_OFF  (OSQ_OFF + 3*COUT)
#define SHIFT_OFF  (SCALE_OFF + CIN)
#define OBNS_OFF   (SHIFT_OFF + CIN)
#define OBNB_OFF   (OBNS_OFF + 3*COUT)
#define ZERO_OFF   INSUM_OFF
#define ZERO_CNT   (2*CIN + 6*COUT)        // 640 floats

// ---- input BN: per-channel sum/sumsq over nodes ----
__global__ __launch_bounds__(256) void k_in_stats(const float* __restrict__ x,
                                                  float* __restrict__ ws) {
    int tid = blockIdx.x * blockDim.x + threadIdx.x;
    int c = tid & (CIN - 1);
    int r0 = tid >> 7;
    int rstride = (gridDim.x * blockDim.x) >> 7;
    float s = 0.f, ss = 0.f;
    for (int r = r0; r < NN; r += rstride) {
        float v = x[(size_t)r * CIN + c];
        s += v; ss += v * v;
    }
    unsafeAtomicAdd(&ws[INSUM_OFF + c], s);
    unsafeAtomicAdd(&ws[INSQ_OFF + c], ss);
}

__global__ void k_in_finalize(const float* __restrict__ g, const float* __restrict__ b,
                              float* __restrict__ ws) {
    int c = threadIdx.x;   // 128 threads
    float mu  = ws[INSUM_OFF + c] * (1.f / NN);
    float var = ws[INSQ_OFF + c] * (1.f / NN) - mu * mu;
    float sc  = g[c] * rsqrtf(var + BN_EPS);
    ws[SCALE_OFF + c] = sc;
    ws[SHIFT_OFF + c] = b[c] - mu * sc;
}

// fold input-BN scale into W1:  W1'[i][k][o] = scale[k]*W1[i][k][o]
__global__ void k_fold(const float* __restrict__ W1, float* __restrict__ ws) {
    int idx = blockIdx.x * blockDim.x + threadIdx.x;   // < 3*128*64
    int k = (idx >> 6) & (CIN - 1);
    ws[W1P_OFF + idx] = ws[SCALE_OFF + k] * W1[idx];
}

// c1[i][o] = sum_k shift[k]*W1[i][k][o]
__global__ void k_c1(const float* __restrict__ W1, float* __restrict__ ws) {
    int i = blockIdx.x, o = threadIdx.x;   // 3 blocks x 64
    float acc = 0.f;
    for (int k = 0; k < CIN; ++k)
        acc = fmaf(ws[SHIFT_OFF + k], W1[i * CIN * COUT + k * COUT + o], acc);
    ws[C1_OFF + i * COUT + o] = acc;
}

// ---- CSR build ----
__global__ __launch_bounds__(256) void k_hist(const int* __restrict__ ei,
                                              int* __restrict__ wsi) {
    int* deg = wsi + DEG_OFF;
    int i = blockIdx.x * blockDim.x + threadIdx.x;
    int stride = gridDim.x * blockDim.x;
    for (int e = i; e < NE; e += stride)
        atomicAdd(&deg[ei[NE + e]], 1);
}

// single-block 1024-thread exclusive scan of deg -> rowptr (+ cursor copy)
__global__ __launch_bounds__(1024) void k_scan(int* __restrict__ wsi) {
    const int* deg = wsi + DEG_OFF;
    int* rowptr = wsi + ROWPTR_OFF;
    int* cursor = wsi + CURSOR_OFF;
    __shared__ int sh[1024];
    int t = threadIdx.x;
    const int CHUNK = (NN + 1023) / 1024;   // 98
    int base = t * CHUNK;
    int lim = NN - base;
    if (lim > CHUNK) lim = CHUNK;
    if (lim < 0) lim = 0;
    int s = 0;
    for (int i = 0; i < lim; ++i) s += deg[base + i];
    sh[t] = s;
    __syncthreads();
    for (int off = 1; off < 1024; off <<= 1) {
        int v = 0;
        if (t >= off) v = sh[t - off];
        __syncthreads();
        sh[t] += v;
        __syncthreads();
    }
    int run = sh[t] - s;   // exclusive prefix of this thread's chunk
    for (int i = 0; i < lim; ++i) {
        rowptr[base + i] = run;
        cursor[base + i] = run;
        run += deg[base + i];
    }
    if (t == 0) rowptr[NN] = NE;
}

__global__ __launch_bounds__(256) void k_fill(const int* __restrict__ ei,
                                              int* __restrict__ wsi) {
    int* cursor = wsi + CURSOR_OFF;
    int* col = wsi + COL_OFF;
    int i = blockIdx.x * blockDim.x + threadIdx.x;
    int stride = gridDim.x * blockDim.x;
    for (int e = i; e < NE; e += stride) {
        int d = ei[NE + e];
        int pos = atomicAdd(&cursor[d], 1);
        col[pos] = ei[e];   // src
    }
}

// y1 = x @ W1' + c1
__global__ __launch_bounds__(256, 2) void k_gemm1(const float* __restrict__ x,
                                                  float* __restrict__ ws, int br) {
    const float* __restrict__ W1p = ws + W1P_OFF + br * CIN * COUT;
    const float* __restrict__ c1  = ws + C1_OFF + br * COUT;
    float* __restrict__ y1 = ws + Y1_OFF;
    int lane = threadIdx.x & 63;
    int wave = (blockIdx.x * blockDim.x + threadIdx.x) >> 6;
    int nw   = (gridDim.x * blockDim.x) >> 6;
    float wk[CIN];
    #pragma unroll
    for (int k = 0; k < CIN; ++k) wk[k] = W1p[k * COUT + lane];
    float c1v = c1[lane];
    for (int n = wave; n < NN; n += nw) {
        const float* __restrict__ xr =
            x + (size_t)__builtin_amdgcn_readfirstlane(n) * CIN;
        float a0 = 0.f, a1 = 0.f, a2 = 0.f, a3 = 0.f;
        #pragma unroll
        for (int k = 0; k < CIN; k += 4) {
            a0 = fmaf(xr[k],     wk[k],     a0);
            a1 = fmaf(xr[k + 1], wk[k + 1], a1);
            a2 = fmaf(xr[k + 2], wk[k + 2], a2);
            a3 = fmaf(xr[k + 3], wk[k + 3], a3);
        }
        y1[(size_t)n * COUT + lane] = (a0 + a1) + (a2 + a3) + c1v;
    }
}

// fused: t = y1[n] + sum_{src in CSR[n]} y1[src]; relu(t+b1) @ W2 + b2 -> out;
// accumulate output-BN stats
__global__ __launch_bounds__(256, 4) void k_gather_l2(const float* __restrict__ W2all,
                                                      const float* __restrict__ b1all,
                                                      const float* __restrict__ b2all,
                                                      float* __restrict__ out,
                                                      float* __restrict__ ws, int br) {
    const float* __restrict__ W2 = W2all + br * COUT * COUT;
    const float* __restrict__ y1 = ws + Y1_OFF;
    const int* __restrict__ rowptr = (const int*)ws + ROWPTR_OFF;
    const int* __restrict__ col    = (const int*)ws + COL_OFF;
    float* osum = ws + OSUM_OFF + br * COUT;
    float* osq  = ws + OSQ_OFF  + br * COUT;
    int lane = threadIdx.x & 63;
    int wave = (blockIdx.x * blockDim.x + threadIdx.x) >> 6;
    int nw   = (gridDim.x * blockDim.x) >> 6;
    float w2k[COUT];
    #pragma unroll
    for (int j = 0; j < COUT; ++j) w2k[j] = W2[j * COUT + lane];
    float b1v = b1all[br * COUT + lane];
    float b2v = b2all[br * COUT + lane];
    float ls = 0.f, lss = 0.f;
    for (int n = wave; n < NN; n += nw) {
        int nn = __builtin_amdgcn_readfirstlane(n);
        int beg = rowptr[nn], end = rowptr[nn + 1];
        float a0 = y1[(size_t)nn * COUT + lane];
        float a1 = 0.f, a2 = 0.f, a3 = 0.f;
        int j = beg;
        for (; j + 3 < end; j += 4) {
            int c0 = col[j], c1 = col[j + 1], c2 = col[j + 2], c3 = col[j + 3];
            a0 += y1[(size_t)c0 * COUT + lane];
            a1 += y1[(size_t)c1 * COUT + lane];
            a2 += y1[(size_t)c2 * COUT + lane];
            a3 += y1[(size_t)c3 * COUT + lane];
        }
        for (; j < end; ++j) a0 += y1[(size_t)col[j] * COUT + lane];
        float t1 = fmaxf((a0 + a1) + (a2 + a3) + b1v, 0.f);
        int t1i = __float_as_int(t1);
        float s0 = b2v, s1 = 0.f, s2 = 0.f, s3 = 0.f;
        #pragma unroll
        for (int k = 0; k < COUT; k += 4) {
            s0 = fmaf(__int_as_float(__builtin_amdgcn_readlane(t1i, k)),     w2k[k],     s0);
            s1 = fmaf(__int_as_float(__builtin_amdgcn_readlane(t1i, k + 1)), w2k[k + 1], s1);
            s2 = fmaf(__int_as_float(__builtin_amdgcn_readlane(t1i, k + 2)), w2k[k + 2], s2);
            s3 = fmaf(__int_as_float(__builtin_amdgcn_readlane(t1i, k + 3)), w2k[k + 3], s3);
        }
        float acc = (s0 + s1) + (s2 + s3);
        out[(size_t)nn * COUT + lane] = acc;
        ls += acc; lss += acc * acc;
    }
    unsafeAtomicAdd(&osum[lane], ls);
    unsafeAtomicAdd(&osq[lane], lss);
}

__global__ void k_obn_final(const float* __restrict__ g, const float* __restrict__ b,
                            float* __restrict__ ws, int br) {
    int o = threadIdx.x;   // 64 threads
    float mu  = ws[OSUM_OFF + br * COUT + o] * (1.f / NN);
    float var = ws[OSQ_OFF  + br * COUT + o] * (1.f / NN) - mu * mu;
    float sc  = g[br * COUT + o] * rsqrtf(var + BN_EPS);
    ws[OBNS_OFF + br * COUT + o] = sc;
    ws[OBNB_OFF + br * COUT + o] = b[br * COUT + o] - mu * sc;
}

// y = tanh(sc[c]*h2 + sh[c]) in-place on d_out section
__global__ __launch_bounds__(256) void k_apply(float* __restrict__ out,
                                               const float* __restrict__ ws, int br) {
    const float* __restrict__ sc = ws + OBNS_OFF + br * COUT;
    const float* __restrict__ sh = ws + OBNB_OFF + br * COUT;
    int idx = blockIdx.x * blockDim.x + threadIdx.x;
    int stride = gridDim.x * blockDim.x;
    const int total = NN * COUT / 4;
    float4* o4 = (float4*)out;
    for (int v = idx; v < total; v += stride) {
        int c = (v & 15) * 4;
        float4 f = o4[v];
        f.x = tanhf(fmaf(f.x, sc[c],     sh[c]));
        f.y = tanhf(fmaf(f.y, sc[c + 1], sh[c + 1]));
        f.z = tanhf(fmaf(f.z, sc[c + 2], sh[c + 2]));
        f.w = tanhf(fmaf(f.w, sc[c + 3], sh[c + 3]));
        o4[v] = f;
    }
}

extern "C" void kernel_launch(void* const* d_in, const int* in_sizes, int n_in,
                              void* d_out, int out_size, void* d_ws, size_t ws_size,
                              hipStream_t stream) {
    const float* x   = (const float*)d_in[0];
    const int*   eip = (const int*)d_in[1];
    const int*   eis = (const int*)d_in[2];
    const int*   eiv = (const int*)d_in[3];
    const float* ig  = (const float*)d_in[4];
    const float* ib  = (const float*)d_in[5];
    const float* W1  = (const float*)d_in[6];
    const float* b1  = (const float*)d_in[7];
    const float* W2  = (const float*)d_in[8];
    const float* b2  = (const float*)d_in[9];
    const float* bng = (const float*)d_in[10];
    const float* bnb = (const float*)d_in[11];
    float* out = (float*)d_out;
    float* ws  = (float*)d_ws;
    int*   wsi = (int*)d_ws;

    hipMemsetAsync(ws + ZERO_OFF, 0, ZERO_CNT * sizeof(float), stream);
    k_in_stats<<<256, 256, 0, stream>>>(x, ws);
    k_in_finalize<<<1, 128, 0, stream>>>(ig, ib, ws);
    k_fold<<<96, 256, 0, stream>>>(W1, ws);
    k_c1<<<3, 64, 0, stream>>>(W1, ws);

    const int* edges[3] = {eip, eis, eiv};
    for (int br = 0; br < 3; ++br) {
        hipMemsetAsync(wsi + DEG_OFF, 0, NN * sizeof(int), stream);
        k_hist<<<512, 256, 0, stream>>>(edges[br], wsi);
        k_scan<<<1, 1024, 0, stream>>>(wsi);
        k_fill<<<512, 256, 0, stream>>>(edges[br], wsi);
        k_gemm1<<<1024, 256, 0, stream>>>(x, ws, br);
        k_gather_l2<<<2048, 256, 0, stream>>>(W2, b1, b2,
                                              out + (size_t)br * NN * COUT, ws, br);
        k_obn_final<<<1, 64, 0, stream>>>(bng, bnb, ws, br);
        k_apply<<<2048, 256, 0, stream>>>(out + (size_t)br * NN * COUT, ws, br);
    }
}

// Round 3
// 1250.091 us; speedup vs baseline: 1.5294x; 1.5294x over previous
//
#include <hip/hip_runtime.h>
#include <math.h>

#define NN   100000
#define NE   1000000
#define CIN  128
#define COUT 64
#define BN_EPS 1e-5f
#define SCAN_BLOCKS 98   // ceil(NN/1024)

// ---- workspace layout (4-byte element offsets) ----
#define Y1_OFF     0                        // NN*COUT floats
#define COL_OFF    6400000                  // 3*NE ints
#define ROWPTR_OFF 9400000                  // 3*(NN+1) ints
#define CURSOR_OFF 9700016                  // 3*NN ints
#define DEG_OFF    10000016                 // 3*NN ints
#define BSUM_OFF   10300016                 // 3*128 ints
#define W1P_OFF    10300400                 // 3*CIN*COUT floats
#define C1_OFF     (W1P_OFF + 3*CIN*COUT)
#define INSUM_OFF  (C1_OFF + 3*COUT)
#define INSQ_OFF   (INSUM_OFF + CIN)
#define OSUM_OFF   (INSQ_OFF + CIN)
#define OSQ_OFF    (OSUM_OFF + 3*COUT)
#define SCALE_OFF  (OSQ_OFF + 3*COUT)
#define SHIFT_OFF  (SCALE_OFF + CIN)
#define OBNS_OFF   (SHIFT_OFF + CIN)
#define OBNB_OFF   (OBNS_OFF + 3*COUT)
#define ZERO_OFF   INSUM_OFF
#define ZERO_CNT   (2*CIN + 6*COUT)         // 640 floats

// ---- input BN: per-channel sum/sumsq over nodes ----
__global__ __launch_bounds__(256) void k_in_stats(const float* __restrict__ x,
                                                  float* __restrict__ ws) {
    int tid = blockIdx.x * blockDim.x + threadIdx.x;
    int c = tid & (CIN - 1);
    int r0 = tid >> 7;
    int rstride = (gridDim.x * blockDim.x) >> 7;
    float s = 0.f, ss = 0.f;
    for (int r = r0; r < NN; r += rstride) {
        float v = x[(size_t)r * CIN + c];
        s += v; ss += v * v;
    }
    unsafeAtomicAdd(&ws[INSUM_OFF + c], s);
    unsafeAtomicAdd(&ws[INSQ_OFF + c], ss);
}

__global__ void k_in_finalize(const float* __restrict__ g, const float* __restrict__ b,
                              float* __restrict__ ws) {
    int c = threadIdx.x;   // 128 threads
    float mu  = ws[INSUM_OFF + c] * (1.f / NN);
    float var = ws[INSQ_OFF + c] * (1.f / NN) - mu * mu;
    float sc  = g[c] * rsqrtf(var + BN_EPS);
    ws[SCALE_OFF + c] = sc;
    ws[SHIFT_OFF + c] = b[c] - mu * sc;
}

// fold input-BN scale into W1:  W1'[i][k][o] = scale[k]*W1[i][k][o]
__global__ void k_fold(const float* __restrict__ W1, float* __restrict__ ws) {
    int idx = blockIdx.x * blockDim.x + threadIdx.x;   // < 3*128*64
    int k = (idx >> 6) & (CIN - 1);
    ws[W1P_OFF + idx] = ws[SCALE_OFF + k] * W1[idx];
}

// c1[i][o] = sum_k shift[k]*W1[i][k][o]
__global__ void k_c1(const float* __restrict__ W1, float* __restrict__ ws) {
    int i = blockIdx.x, o = threadIdx.x;   // 3 blocks x 64
    float acc = 0.f;
    for (int k = 0; k < CIN; ++k)
        acc = fmaf(ws[SHIFT_OFF + k], W1[i * CIN * COUT + k * COUT + o], acc);
    ws[C1_OFF + i * COUT + o] = acc;
}

// ---- CSR build (all 3 branches; blockIdx.y = branch) ----
__global__ __launch_bounds__(256) void k_hist3(const int* __restrict__ e0,
                                               const int* __restrict__ e1,
                                               const int* __restrict__ e2,
                                               int* __restrict__ wsi) {
    int z = blockIdx.y;
    const int* ei = (z == 0) ? e0 : (z == 1) ? e1 : e2;
    int* deg = wsi + DEG_OFF + z * NN;
    int i = blockIdx.x * blockDim.x + threadIdx.x;
    int stride = gridDim.x * blockDim.x;
    for (int e = i; e < NE; e += stride)
        atomicAdd(&deg[ei[NE + e]], 1);
}

// phase A: per-block sums of deg
__global__ __launch_bounds__(1024) void k_scan_a(int* __restrict__ wsi) {
    int z = blockIdx.y;
    const int* deg = wsi + DEG_OFF + z * NN;
    __shared__ int sh[1024];
    int t = threadIdx.x;
    int idx = blockIdx.x * 1024 + t;
    sh[t] = (idx < NN) ? deg[idx] : 0;
    __syncthreads();
    for (int off = 512; off > 0; off >>= 1) {
        if (t < off) sh[t] += sh[t + off];
        __syncthreads();
    }
    if (t == 0) wsi[BSUM_OFF + z * 128 + blockIdx.x] = sh[0];
}

// phase B: exclusive scan of the SCAN_BLOCKS block sums (per branch)
__global__ __launch_bounds__(128) void k_scan_b(int* __restrict__ wsi) {
    int z = blockIdx.x;
    int* bsum = wsi + BSUM_OFF + z * 128;
    __shared__ int sh[128];
    int t = threadIdx.x;
    int v = (t < SCAN_BLOCKS) ? bsum[t] : 0;
    sh[t] = v;
    __syncthreads();
    for (int off = 1; off < 128; off <<= 1) {
        int u = 0;
        if (t >= off) u = sh[t - off];
        __syncthreads();
        sh[t] += u;
        __syncthreads();
    }
    bsum[t] = sh[t] - v;   // exclusive prefix
}

// phase C: block-local scan + block offset -> rowptr, cursor
__global__ __launch_bounds__(1024) void k_scan_c(int* __restrict__ wsi) {
    int z = blockIdx.y;
    const int* deg = wsi + DEG_OFF + z * NN;
    int* rowptr = wsi + ROWPTR_OFF + z * (NN + 1);
    int* cursor = wsi + CURSOR_OFF + z * NN;
    __shared__ int sh[1024];
    int t = threadIdx.x;
    int idx = blockIdx.x * 1024 + t;
    int v = (idx < NN) ? deg[idx] : 0;
    sh[t] = v;
    __syncthreads();
    for (int off = 1; off < 1024; off <<= 1) {
        int u = 0;
        if (t >= off) u = sh[t - off];
        __syncthreads();
        sh[t] += u;
        __syncthreads();
    }
    if (idx < NN) {
        int excl = sh[t] - v + wsi[BSUM_OFF + z * 128 + blockIdx.x];
        rowptr[idx] = excl;
        cursor[idx] = excl;
    }
    if (blockIdx.x == 0 && t == 0) rowptr[NN] = NE;
}

__global__ __launch_bounds__(256) void k_fill3(const int* __restrict__ e0,
                                               const int* __restrict__ e1,
                                               const int* __restrict__ e2,
                                               int* __restrict__ wsi) {
    int z = blockIdx.y;
    const int* ei = (z == 0) ? e0 : (z == 1) ? e1 : e2;
    int* cursor = wsi + CURSOR_OFF + z * NN;
    int* col = wsi + COL_OFF + z * NE;
    int i = blockIdx.x * blockDim.x + threadIdx.x;
    int stride = gridDim.x * blockDim.x;
    for (int e = i; e < NE; e += stride) {
        int d = ei[NE + e];
        int pos = atomicAdd(&cursor[d], 1);
        col[pos] = ei[e];   // src
    }
}

// y1 = x @ W1' + c1
__global__ __launch_bounds__(256, 2) void k_gemm1(const float* __restrict__ x,
                                                  float* __restrict__ ws, int br) {
    const float* __restrict__ W1p = ws + W1P_OFF + br * CIN * COUT;
    const float* __restrict__ c1  = ws + C1_OFF + br * COUT;
    float* __restrict__ y1 = ws + Y1_OFF;
    int lane = threadIdx.x & 63;
    int wave = (blockIdx.x * blockDim.x + threadIdx.x) >> 6;
    int nw   = (gridDim.x * blockDim.x) >> 6;
    float wk[CIN];
    #pragma unroll
    for (int k = 0; k < CIN; ++k) wk[k] = W1p[k * COUT + lane];
    float c1v = c1[lane];
    for (int n = wave; n < NN; n += nw) {
        const float* __restrict__ xr =
            x + (size_t)__builtin_amdgcn_readfirstlane(n) * CIN;
        float a0 = 0.f, a1 = 0.f, a2 = 0.f, a3 = 0.f;
        #pragma unroll
        for (int k = 0; k < CIN; k += 4) {
            a0 = fmaf(xr[k],     wk[k],     a0);
            a1 = fmaf(xr[k + 1], wk[k + 1], a1);
            a2 = fmaf(xr[k + 2], wk[k + 2], a2);
            a3 = fmaf(xr[k + 3], wk[k + 3], a3);
        }
        y1[(size_t)n * COUT + lane] = (a0 + a1) + (a2 + a3) + c1v;
    }
}

// fused: t = y1[n] + sum_{src in CSR[n]} y1[src]; relu(t+b1) @ W2 + b2 -> out;
// accumulate output-BN stats
__global__ __launch_bounds__(256, 4) void k_gather_l2(const float* __restrict__ W2all,
                                                      const float* __restrict__ b1all,
                                                      const float* __restrict__ b2all,
                                                      float* __restrict__ out,
                                                      float* __restrict__ ws, int br) {
    const float* __restrict__ W2 = W2all + br * COUT * COUT;
    const float* __restrict__ y1 = ws + Y1_OFF;
    const int* __restrict__ rowptr = (const int*)ws + ROWPTR_OFF + br * (NN + 1);
    const int* __restrict__ col    = (const int*)ws + COL_OFF + br * NE;
    float* osum = ws + OSUM_OFF + br * COUT;
    float* osq  = ws + OSQ_OFF  + br * COUT;
    int lane = threadIdx.x & 63;
    int wave = (blockIdx.x * blockDim.x + threadIdx.x) >> 6;
    int nw   = (gridDim.x * blockDim.x) >> 6;
    float w2k[COUT];
    #pragma unroll
    for (int j = 0; j < COUT; ++j) w2k[j] = W2[j * COUT + lane];
    float b1v = b1all[br * COUT + lane];
    float b2v = b2all[br * COUT + lane];
    float ls = 0.f, lss = 0.f;
    for (int n = wave; n < NN; n += nw) {
        int nn = __builtin_amdgcn_readfirstlane(n);
        int beg = rowptr[nn], end = rowptr[nn + 1];
        float a0 = y1[(size_t)nn * COUT + lane];
        float a1 = 0.f, a2 = 0.f, a3 = 0.f;
        int j = beg;
        for (; j + 3 < end; j += 4) {
            int c0 = col[j], c1 = col[j + 1], c2 = col[j + 2], c3 = col[j + 3];
            a0 += y1[(size_t)c0 * COUT + lane];
            a1 += y1[(size_t)c1 * COUT + lane];
            a2 += y1[(size_t)c2 * COUT + lane];
            a3 += y1[(size_t)c3 * COUT + lane];
        }
        for (; j < end; ++j) a0 += y1[(size_t)col[j] * COUT + lane];
        float t1 = fmaxf((a0 + a1) + (a2 + a3) + b1v, 0.f);
        int t1i = __float_as_int(t1);
        float s0 = b2v, s1 = 0.f, s2 = 0.f, s3 = 0.f;
        #pragma unroll
        for (int k = 0; k < COUT; k += 4) {
            s0 = fmaf(__int_as_float(__builtin_amdgcn_readlane(t1i, k)),     w2k[k],     s0);
            s1 = fmaf(__int_as_float(__builtin_amdgcn_readlane(t1i, k + 1)), w2k[k + 1], s1);
            s2 = fmaf(__int_as_float(__builtin_amdgcn_readlane(t1i, k + 2)), w2k[k + 2], s2);
            s3 = fmaf(__int_as_float(__builtin_amdgcn_readlane(t1i, k + 3)), w2k[k + 3], s3);
        }
        float acc = (s0 + s1) + (s2 + s3);
        out[(size_t)nn * COUT + lane] = acc;
        ls += acc; lss += acc * acc;
    }
    unsafeAtomicAdd(&osum[lane], ls);
    unsafeAtomicAdd(&osq[lane], lss);
}

__global__ void k_obn_final(const float* __restrict__ g, const float* __restrict__ b,
                            float* __restrict__ ws, int br) {
    int o = threadIdx.x;   // 64 threads
    float mu  = ws[OSUM_OFF + br * COUT + o] * (1.f / NN);
    float var = ws[OSQ_OFF  + br * COUT + o] * (1.f / NN) - mu * mu;
    float sc  = g[br * COUT + o] * rsqrtf(var + BN_EPS);
    ws[OBNS_OFF + br * COUT + o] = sc;
    ws[OBNB_OFF + br * COUT + o] = b[br * COUT + o] - mu * sc;
}

// y = tanh(sc[c]*h2 + sh[c]) in-place on d_out section
__global__ __launch_bounds__(256) void k_apply(float* __restrict__ out,
                                               const float* __restrict__ ws, int br) {
    const float* __restrict__ sc = ws + OBNS_OFF + br * COUT;
    const float* __restrict__ sh = ws + OBNB_OFF + br * COUT;
    int idx = blockIdx.x * blockDim.x + threadIdx.x;
    int stride = gridDim.x * blockDim.x;
    const int total = NN * COUT / 4;
    float4* o4 = (float4*)out;
    for (int v = idx; v < total; v += stride) {
        int c = (v & 15) * 4;
        float4 f = o4[v];
        f.x = tanhf(fmaf(f.x, sc[c],     sh[c]));
        f.y = tanhf(fmaf(f.y, sc[c + 1], sh[c + 1]));
        f.z = tanhf(fmaf(f.z, sc[c + 2], sh[c + 2]));
        f.w = tanhf(fmaf(f.w, sc[c + 3], sh[c + 3]));
        o4[v] = f;
    }
}

extern "C" void kernel_launch(void* const* d_in, const int* in_sizes, int n_in,
                              void* d_out, int out_size, void* d_ws, size_t ws_size,
                              hipStream_t stream) {
    const float* x   = (const float*)d_in[0];
    const int*   eip = (const int*)d_in[1];
    const int*   eis = (const int*)d_in[2];
    const int*   eiv = (const int*)d_in[3];
    const float* ig  = (const float*)d_in[4];
    const float* ib  = (const float*)d_in[5];
    const float* W1  = (const float*)d_in[6];
    const float* b1  = (const float*)d_in[7];
    const float* W2  = (const float*)d_in[8];
    const float* b2  = (const float*)d_in[9];
    const float* bng = (const float*)d_in[10];
    const float* bnb = (const float*)d_in[11];
    float* out = (float*)d_out;
    float* ws  = (float*)d_ws;
    int*   wsi = (int*)d_ws;

    hipMemsetAsync(ws + ZERO_OFF, 0, ZERO_CNT * sizeof(float), stream);
    hipMemsetAsync(wsi + DEG_OFF, 0, 3 * NN * sizeof(int), stream);

    k_in_stats<<<256, 256, 0, stream>>>(x, ws);
    k_in_finalize<<<1, 128, 0, stream>>>(ig, ib, ws);
    k_fold<<<96, 256, 0, stream>>>(W1, ws);
    k_c1<<<3, 64, 0, stream>>>(W1, ws);

    // CSR build for all 3 branches
    k_hist3<<<dim3(512, 3), 256, 0, stream>>>(eip, eis, eiv, wsi);
    k_scan_a<<<dim3(SCAN_BLOCKS, 3), 1024, 0, stream>>>(wsi);
    k_scan_b<<<3, 128, 0, stream>>>(wsi);
    k_scan_c<<<dim3(SCAN_BLOCKS, 3), 1024, 0, stream>>>(wsi);
    k_fill3<<<dim3(512, 3), 256, 0, stream>>>(eip, eis, eiv, wsi);

    for (int br = 0; br < 3; ++br) {
        k_gemm1<<<1024, 256, 0, stream>>>(x, ws, br);
        k_gather_l2<<<2048, 256, 0, stream>>>(W2, b1, b2,
                                              out + (size_t)br * NN * COUT, ws, br);
        k_obn_final<<<1, 64, 0, stream>>>(bng, bnb, ws, br);
        k_apply<<<2048, 256, 0, stream>>>(out + (size_t)br * NN * COUT, ws, br);
    }
}

// Round 4
// 1010.655 us; speedup vs baseline: 1.8918x; 1.2369x over previous
//
#include <hip/hip_runtime.h>
#include <math.h>

#define NN   100000
#define NE   1000000
#define CIN  128
#define COUT 64
#define BN_EPS 1e-5f
#define NB    391      // ceil(NN/256) level-1 buckets (dst>>8)
#define NBLK1 128      // blocks per branch in sort phases 1/2
#define CHUNK_E ((NE + NBLK1 - 1) / NBLK1)   // 7813

// ---- workspace layout (4-byte element offsets) ----
// temp (int2 x NE x 3 branches) occupies ints [0, 6M) and OVERLAPS y1
// (floats [0, 6.4M)); sort fully consumes temp before gemm1 writes y1.
#define Y1_OFF     0                        // NN*COUT floats
#define COL_OFF    6400000                  // 3*NE ints
#define ROWPTR_OFF 9400000                  // 3*(NN+1) ints
#define OFF_OFF    9700016                  // 3*NB*NBLK1 ints (150144)
#define W1P_OFF    9850160                  // 3*CIN*COUT floats
#define C1_OFF     (W1P_OFF + 3*CIN*COUT)
#define INSUM_OFF  (C1_OFF + 3*COUT)
#define INSQ_OFF   (INSUM_OFF + CIN)
#define OSUM_OFF   (INSQ_OFF + CIN)
#define OSQ_OFF    (OSUM_OFF + 3*COUT)
#define SCALE_OFF  (OSQ_OFF + 3*COUT)
#define SHIFT_OFF  (SCALE_OFF + CIN)
#define OBNS_OFF   (SHIFT_OFF + CIN)
#define OBNB_OFF   (OBNS_OFF + 3*COUT)
#define ZERO_OFF   INSUM_OFF
#define ZERO_CNT   (2*CIN + 6*COUT)         // 640 floats

// ---- input BN: per-channel sum/sumsq over nodes ----
__global__ __launch_bounds__(256) void k_in_stats(const float* __restrict__ x,
                                                  float* __restrict__ ws) {
    int tid = blockIdx.x * blockDim.x + threadIdx.x;
    int c = tid & (CIN - 1);
    int r0 = tid >> 7;
    int rstride = (gridDim.x * blockDim.x) >> 7;
    float s = 0.f, ss = 0.f;
    for (int r = r0; r < NN; r += rstride) {
        float v = x[(size_t)r * CIN + c];
        s += v; ss += v * v;
    }
    unsafeAtomicAdd(&ws[INSUM_OFF + c], s);
    unsafeAtomicAdd(&ws[INSQ_OFF + c], ss);
}

__global__ void k_in_finalize(const float* __restrict__ g, const float* __restrict__ b,
                              float* __restrict__ ws) {
    int c = threadIdx.x;   // 128 threads
    float mu  = ws[INSUM_OFF + c] * (1.f / NN);
    float var = ws[INSQ_OFF + c] * (1.f / NN) - mu * mu;
    float sc  = g[c] * rsqrtf(var + BN_EPS);
    ws[SCALE_OFF + c] = sc;
    ws[SHIFT_OFF + c] = b[c] - mu * sc;
}

// fold input-BN scale into W1:  W1'[i][k][o] = scale[k]*W1[i][k][o]
__global__ void k_fold(const float* __restrict__ W1, float* __restrict__ ws) {
    int idx = blockIdx.x * blockDim.x + threadIdx.x;   // < 3*128*64
    int k = (idx >> 6) & (CIN - 1);
    ws[W1P_OFF + idx] = ws[SCALE_OFF + k] * W1[idx];
}

// c1[i][o] = sum_k shift[k]*W1[i][k][o]
__global__ void k_c1(const float* __restrict__ W1, float* __restrict__ ws) {
    int i = blockIdx.x, o = threadIdx.x;   // 3 blocks x 64
    float acc = 0.f;
    for (int k = 0; k < CIN; ++k)
        acc = fmaf(ws[SHIFT_OFF + k], W1[i * CIN * COUT + k * COUT + o], acc);
    ws[C1_OFF + i * COUT + o] = acc;
}

// ---- two-level bucket sort of edges by dst ----
// phase 1: per-(block,bucket) histogram of dst>>8 via LDS
__global__ __launch_bounds__(256) void k_sort_hist(const int* __restrict__ e0,
                                                   const int* __restrict__ e1,
                                                   const int* __restrict__ e2,
                                                   int* __restrict__ wsi) {
    int z = blockIdx.y;
    const int* ei = (z == 0) ? e0 : (z == 1) ? e1 : e2;
    __shared__ int h[NB];
    for (int i = threadIdx.x; i < NB; i += 256) h[i] = 0;
    __syncthreads();
    int beg = blockIdx.x * CHUNK_E;
    int end = min(NE, beg + CHUNK_E);
    for (int e = beg + threadIdx.x; e < end; e += 256)
        atomicAdd(&h[ei[NE + e] >> 8], 1);
    __syncthreads();
    int* off = wsi + OFF_OFF + z * (NB * NBLK1);
    for (int i = threadIdx.x; i < NB; i += 256)
        off[i * NBLK1 + blockIdx.x] = h[i];
}

// phase 2: exclusive scan of the NB*NBLK1 counts (bucket-major), per branch
__global__ __launch_bounds__(1024) void k_sort_scan(int* __restrict__ wsi) {
    int z = blockIdx.x;
    int* off = wsi + OFF_OFF + z * (NB * NBLK1);
    const int TOT = NB * NBLK1;              // 50048
    const int CH = (TOT + 1023) / 1024;      // 49
    __shared__ int sh[1024];
    int t = threadIdx.x;
    int base = t * CH;
    int s = 0;
    for (int i = 0; i < CH; ++i) {
        int idx = base + i;
        if (idx < TOT) s += off[idx];
    }
    sh[t] = s;
    __syncthreads();
    for (int o = 1; o < 1024; o <<= 1) {
        int v = (t >= o) ? sh[t - o] : 0;
        __syncthreads();
        sh[t] += v;
        __syncthreads();
    }
    int run = sh[t] - s;
    for (int i = 0; i < CH; ++i) {
        int idx = base + i;
        if (idx < TOT) {
            int v = off[idx];
            off[idx] = run;
            run += v;
        }
    }
}

// phase 3: scatter edges into bucket-contiguous temp (int2: dst,src)
__global__ __launch_bounds__(256) void k_sort_scatter(const int* __restrict__ e0,
                                                      const int* __restrict__ e1,
                                                      const int* __restrict__ e2,
                                                      int* __restrict__ wsi) {
    int z = blockIdx.y;
    const int* ei = (z == 0) ? e0 : (z == 1) ? e1 : e2;
    const int* off = wsi + OFF_OFF + z * (NB * NBLK1);
    int2* temp = (int2*)wsi + (size_t)z * NE;
    __shared__ int cur[NB];
    for (int i = threadIdx.x; i < NB; i += 256)
        cur[i] = off[i * NBLK1 + blockIdx.x];
    __syncthreads();
    int beg = blockIdx.x * CHUNK_E;
    int end = min(NE, beg + CHUNK_E);
    for (int e = beg + threadIdx.x; e < end; e += 256) {
        int d = ei[NE + e];
        int s = ei[e];
        int pos = atomicAdd(&cur[d >> 8], 1);
        temp[pos] = make_int2(d, s);
    }
}

// phase 4: per-bucket counting sort (256 dsts) -> col (coalesced) + rowptr
__global__ __launch_bounds__(256) void k_bucket(int* __restrict__ wsi) {
    int z = blockIdx.y, bk = blockIdx.x;
    const int* off = wsi + OFF_OFF + z * (NB * NBLK1);
    const int2* temp = (const int2*)wsi + (size_t)z * NE;
    int* col    = wsi + COL_OFF + z * NE;
    int* rowptr = wsi + ROWPTR_OFF + z * (NN + 1);
    int bs = off[bk * NBLK1];
    int be = (bk + 1 < NB) ? off[(bk + 1) * NBLK1] : NE;
    __shared__ int h[256], sc[256], cur[256];
    int t = threadIdx.x;
    h[t] = 0;
    __syncthreads();
    for (int e = bs + t; e < be; e += 256)
        atomicAdd(&h[temp[e].x & 255], 1);
    __syncthreads();
    int v = h[t];
    sc[t] = v;
    __syncthreads();
    for (int o = 1; o < 256; o <<= 1) {
        int u = (t >= o) ? sc[t - o] : 0;
        __syncthreads();
        sc[t] += u;
        __syncthreads();
    }
    int excl = sc[t] - v;
    int gd = bk * 256 + t;
    if (gd <= NN) rowptr[gd] = bs + excl;   // gd==NN lands on empty tail -> NE
    cur[t] = excl;
    __syncthreads();
    for (int e = bs + t; e < be; e += 256) {
        int2 p = temp[e];
        int pos = atomicAdd(&cur[p.x & 255], 1);
        col[bs + pos] = p.y;
    }
}

// y1 = x @ W1' + c1
__global__ __launch_bounds__(256, 2) void k_gemm1(const float* __restrict__ x,
                                                  float* __restrict__ ws, int br) {
    const float* __restrict__ W1p = ws + W1P_OFF + br * CIN * COUT;
    const float* __restrict__ c1  = ws + C1_OFF + br * COUT;
    float* __restrict__ y1 = ws + Y1_OFF;
    int lane = threadIdx.x & 63;
    int wave = (blockIdx.x * blockDim.x + threadIdx.x) >> 6;
    int nw   = (gridDim.x * blockDim.x) >> 6;
    float wk[CIN];
    #pragma unroll
    for (int k = 0; k < CIN; ++k) wk[k] = W1p[k * COUT + lane];
    float c1v = c1[lane];
    for (int n = wave; n < NN; n += nw) {
        const float* __restrict__ xr =
            x + (size_t)__builtin_amdgcn_readfirstlane(n) * CIN;
        float a0 = 0.f, a1 = 0.f, a2 = 0.f, a3 = 0.f;
        #pragma unroll
        for (int k = 0; k < CIN; k += 4) {
            a0 = fmaf(xr[k],     wk[k],     a0);
            a1 = fmaf(xr[k + 1], wk[k + 1], a1);
            a2 = fmaf(xr[k + 2], wk[k + 2], a2);
            a3 = fmaf(xr[k + 3], wk[k + 3], a3);
        }
        y1[(size_t)n * COUT + lane] = (a0 + a1) + (a2 + a3) + c1v;
    }
}

// fused: t = y1[n] + sum_{src in CSR[n]} y1[src]; relu(t+b1) @ W2 + b2 -> out;
// accumulate output-BN stats
__global__ __launch_bounds__(256, 4) void k_gather_l2(const float* __restrict__ W2all,
                                                      const float* __restrict__ b1all,
                                                      const float* __restrict__ b2all,
                                                      float* __restrict__ out,
                                                      float* __restrict__ ws, int br) {
    const float* __restrict__ W2 = W2all + br * COUT * COUT;
    const float* __restrict__ y1 = ws + Y1_OFF;
    const int* __restrict__ rowptr = (const int*)ws + ROWPTR_OFF + br * (NN + 1);
    const int* __restrict__ col    = (const int*)ws + COL_OFF + br * NE;
    float* osum = ws + OSUM_OFF + br * COUT;
    float* osq  = ws + OSQ_OFF  + br * COUT;
    int lane = threadIdx.x & 63;
    int wave = (blockIdx.x * blockDim.x + threadIdx.x) >> 6;
    int nw   = (gridDim.x * blockDim.x) >> 6;
    float w2k[COUT];
    #pragma unroll
    for (int j = 0; j < COUT; ++j) w2k[j] = W2[j * COUT + lane];
    float b1v = b1all[br * COUT + lane];
    float b2v = b2all[br * COUT + lane];
    float ls = 0.f, lss = 0.f;
    for (int n = wave; n < NN; n += nw) {
        int nn = __builtin_amdgcn_readfirstlane(n);
        int beg = rowptr[nn], end = rowptr[nn + 1];
        float a0 = y1[(size_t)nn * COUT + lane];
        float a1 = 0.f, a2 = 0.f, a3 = 0.f;
        int j = beg;
        for (; j + 3 < end; j += 4) {
            int c0 = col[j], c1 = col[j + 1], c2 = col[j + 2], c3 = col[j + 3];
            a0 += y1[(size_t)c0 * COUT + lane];
            a1 += y1[(size_t)c1 * COUT + lane];
            a2 += y1[(size_t)c2 * COUT + lane];
            a3 += y1[(size_t)c3 * COUT + lane];
        }
        for (; j < end; ++j) a0 += y1[(size_t)col[j] * COUT + lane];
        float t1 = fmaxf((a0 + a1) + (a2 + a3) + b1v, 0.f);
        int t1i = __float_as_int(t1);
        float s0 = b2v, s1 = 0.f, s2 = 0.f, s3 = 0.f;
        #pragma unroll
        for (int k = 0; k < COUT; k += 4) {
            s0 = fmaf(__int_as_float(__builtin_amdgcn_readlane(t1i, k)),     w2k[k],     s0);
            s1 = fmaf(__int_as_float(__builtin_amdgcn_readlane(t1i, k + 1)), w2k[k + 1], s1);
            s2 = fmaf(__int_as_float(__builtin_amdgcn_readlane(t1i, k + 2)), w2k[k + 2], s2);
            s3 = fmaf(__int_as_float(__builtin_amdgcn_readlane(t1i, k + 3)), w2k[k + 3], s3);
        }
        float acc = (s0 + s1) + (s2 + s3);
        out[(size_t)nn * COUT + lane] = acc;
        ls += acc; lss += acc * acc;
    }
    unsafeAtomicAdd(&osum[lane], ls);
    unsafeAtomicAdd(&osq[lane], lss);
}

__global__ void k_obn_final(const float* __restrict__ g, const float* __restrict__ b,
                            float* __restrict__ ws, int br) {
    int o = threadIdx.x;   // 64 threads
    float mu  = ws[OSUM_OFF + br * COUT + o] * (1.f / NN);
    float var = ws[OSQ_OFF  + br * COUT + o] * (1.f / NN) - mu * mu;
    float sc  = g[br * COUT + o] * rsqrtf(var + BN_EPS);
    ws[OBNS_OFF + br * COUT + o] = sc;
    ws[OBNB_OFF + br * COUT + o] = b[br * COUT + o] - mu * sc;
}

// y = tanh(sc[c]*h2 + sh[c]) in-place on d_out section
__global__ __launch_bounds__(256) void k_apply(float* __restrict__ out,
                                               const float* __restrict__ ws, int br) {
    const float* __restrict__ sc = ws + OBNS_OFF + br * COUT;
    const float* __restrict__ sh = ws + OBNB_OFF + br * COUT;
    int idx = blockIdx.x * blockDim.x + threadIdx.x;
    int stride = gridDim.x * blockDim.x;
    const int total = NN * COUT / 4;
    float4* o4 = (float4*)out;
    for (int v = idx; v < total; v += stride) {
        int c = (v & 15) * 4;
        float4 f = o4[v];
        f.x = tanhf(fmaf(f.x, sc[c],     sh[c]));
        f.y = tanhf(fmaf(f.y, sc[c + 1], sh[c + 1]));
        f.z = tanhf(fmaf(f.z, sc[c + 2], sh[c + 2]));
        f.w = tanhf(fmaf(f.w, sc[c + 3], sh[c + 3]));
        o4[v] = f;
    }
}

extern "C" void kernel_launch(void* const* d_in, const int* in_sizes, int n_in,
                              void* d_out, int out_size, void* d_ws, size_t ws_size,
                              hipStream_t stream) {
    const float* x   = (const float*)d_in[0];
    const int*   eip = (const int*)d_in[1];
    const int*   eis = (const int*)d_in[2];
    const int*   eiv = (const int*)d_in[3];
    const float* ig  = (const float*)d_in[4];
    const float* ib  = (const float*)d_in[5];
    const float* W1  = (const float*)d_in[6];
    const float* b1  = (const float*)d_in[7];
    const float* W2  = (const float*)d_in[8];
    const float* b2  = (const float*)d_in[9];
    const float* bng = (const float*)d_in[10];
    const float* bnb = (const float*)d_in[11];
    float* out = (float*)d_out;
    float* ws  = (float*)d_ws;
    int*   wsi = (int*)d_ws;

    hipMemsetAsync(ws + ZERO_OFF, 0, ZERO_CNT * sizeof(float), stream);

    k_in_stats<<<256, 256, 0, stream>>>(x, ws);
    k_in_finalize<<<1, 128, 0, stream>>>(ig, ib, ws);
    k_fold<<<96, 256, 0, stream>>>(W1, ws);
    k_c1<<<3, 64, 0, stream>>>(W1, ws);

    // two-level bucket sort -> CSR for all 3 branches (consumes temp, which
    // overlaps y1; all sort kernels complete before first k_gemm1)
    k_sort_hist<<<dim3(NBLK1, 3), 256, 0, stream>>>(eip, eis, eiv, wsi);
    k_sort_scan<<<3, 1024, 0, stream>>>(wsi);
    k_sort_scatter<<<dim3(NBLK1, 3), 256, 0, stream>>>(eip, eis, eiv, wsi);
    k_bucket<<<dim3(NB, 3), 256, 0, stream>>>(wsi);

    for (int br = 0; br < 3; ++br) {
        k_gemm1<<<1024, 256, 0, stream>>>(x, ws, br);
        k_gather_l2<<<2048, 256, 0, stream>>>(W2, b1, b2,
                                              out + (size_t)br * NN * COUT, ws, br);
        k_obn_final<<<1, 64, 0, stream>>>(bng, bnb, ws, br);
        k_apply<<<2048, 256, 0, stream>>>(out + (size_t)br * NN * COUT, ws, br);
    }
}